// Round 1
// baseline (551.086 us; speedup 1.0000x reference)
//
#include <hip/hip_runtime.h>
#include <math.h>

#define BB 256
#define II 2048
#define DD 8
#define JJ 10
#define EE 16
#define BTILE 16
#define ICH 64

// ws layout (floats): s0[2560*16] | s1 | s2 | o_eff   (4 * 40960 floats = 640 KB)

template<int PASS>
__global__ __launch_bounds__(256)
void routing_pass(const float* __restrict__ x, const float* __restrict__ W,
                  const float* __restrict__ o_eff, float* __restrict__ s_out,
                  float* __restrict__ out) {
  __shared__ float w_lds[10 * 132];                       // W[:,i,:,:], padded row stride
  __shared__ float c_tile[(PASS == 2) ? (BTILE * 10 * 68) : 4]; // padded for float4 + banks

  const int t = threadIdx.x;
  const int g = t >> 4;          // 0..15 -> b_local
  const int j = t & 15;          // 0..15, valid j < 10
  const int b = blockIdx.y * BTILE + g;
  const int i0 = blockIdx.x * ICH;

  float o_reg[EE];
  if (j < JJ) {
    const float* op = o_eff + ((size_t)(b * JJ + j)) * EE;
#pragma unroll
    for (int e = 0; e < EE; ++e) o_reg[e] = op[e];
  } else {
#pragma unroll
    for (int e = 0; e < EE; ++e) o_reg[e] = 0.f;
  }

  float acc[EE];
#pragma unroll
  for (int e = 0; e < EE; ++e) acc[e] = 0.f;

  for (int il = 0; il < ICH; ++il) {
    const int i = i0 + il;
    __syncthreads();
    // stage W[:, i, :, :] -> LDS : 1280 floats = 320 float4
    for (int f = t; f < 320; f += 256) {
      const int jj = f >> 5, r = f & 31;
      const float4 v = *reinterpret_cast<const float4*>(
          W + ((size_t)(jj * II + i)) * (EE * DD) + r * 4);
      *reinterpret_cast<float4*>(&w_lds[jj * 132 + r * 4]) = v;
    }
    __syncthreads();

    float xv[DD];
    {
      const float4* xp = reinterpret_cast<const float4*>(x + ((size_t)(b * II + i)) * DD);
      const float4 a0 = xp[0], a1 = xp[1];
      xv[0] = a0.x; xv[1] = a0.y; xv[2] = a0.z; xv[3] = a0.w;
      xv[4] = a1.x; xv[5] = a1.y; xv[6] = a1.z; xv[7] = a1.w;
    }

    float uh[EE];
    float l;
    if (j < JJ) {
      const float* wr = &w_lds[j * 132];
#pragma unroll
      for (int e = 0; e < EE; ++e) {
        float a = 0.f;
#pragma unroll
        for (int d = 0; d < DD; ++d) a = fmaf(xv[d], wr[e * 8 + d], a);
        uh[e] = a;
      }
      l = 0.f;
#pragma unroll
      for (int e = 0; e < EE; ++e) l = fmaf(o_reg[e], uh[e], l);
    } else {
#pragma unroll
      for (int e = 0; e < EE; ++e) uh[e] = 0.f;
      l = -INFINITY;
    }

    // softmax over the 16-lane j-group
    float m = l;
#pragma unroll
    for (int off = 8; off >= 1; off >>= 1) m = fmaxf(m, __shfl_xor(m, off, 16));
    const float p = (j < JJ) ? __expf(l - m) : 0.f;
    float su = p;
#pragma unroll
    for (int off = 8; off >= 1; off >>= 1) su += __shfl_xor(su, off, 16);
    const float c = p / su;

    if (j < JJ) {
#pragma unroll
      for (int e = 0; e < EE; ++e) acc[e] = fmaf(c, uh[e], acc[e]);
      if (PASS == 2) c_tile[(g * 10 + j) * 68 + il] = c;
    }
  }

  if (j < JJ) {
    float* sp = s_out + ((size_t)(b * JJ + j)) * EE;
#pragma unroll
    for (int e = 0; e < EE; ++e) atomicAdd(&sp[e], acc[e]);
  }

  if (PASS == 2) {
    __syncthreads();
    // coalesced write of c rows: 160 rows x 64 floats
    for (int f = t; f < BTILE * 10 * (ICH / 4); f += 256) {
      const int row = f >> 4;   // ICH/4 = 16 float4 per row
      const int q = f & 15;
      const int gg = row / 10, jj = row % 10;
      const float4 v = *reinterpret_cast<const float4*>(&c_tile[row * 68 + q * 4]);
      float* dst = out + ((size_t)((blockIdx.y * BTILE + gg) * JJ + jj)) * 2064 + 16 + i0 + q * 4;
      *reinterpret_cast<float4*>(dst) = v;
    }
  }
}

__global__ __launch_bounds__(256)
void squash_update(const float* __restrict__ s, float* __restrict__ o_eff,
                   float* __restrict__ out, int pass) {
  const int idx = blockIdx.x * blockDim.x + threadIdx.x;
  if (idx >= BB * JJ) return;
  const float* sp = s + (size_t)idx * EE;
  float v[EE];
  float s2 = 0.f;
#pragma unroll
  for (int e = 0; e < EE; ++e) { v[e] = sp[e]; s2 = fmaf(v[e], v[e], s2); }
  const float scale = s2 / ((1.f + s2) * sqrtf(s2 + 1e-7f));
  if (pass == 0) {
    float* op = o_eff + (size_t)idx * EE;
#pragma unroll
    for (int e = 0; e < EE; ++e) op[e] = scale * v[e];
  } else if (pass == 1) {
    float* op = o_eff + (size_t)idx * EE;
#pragma unroll
    for (int e = 0; e < EE; ++e) op[e] += scale * v[e];
  } else {
    float* dst = out + (size_t)idx * 2064;
#pragma unroll
    for (int e = 0; e < EE; ++e) dst[e] = scale * v[e];
  }
}

extern "C" void kernel_launch(void* const* d_in, const int* in_sizes, int n_in,
                              void* d_out, int out_size, void* d_ws, size_t ws_size,
                              hipStream_t stream) {
  const float* x = (const float*)d_in[0];   // [256,2048,8]
  const float* W = (const float*)d_in[1];   // [10,2048,16,8]
  float* out = (float*)d_out;               // [256,10,2064]
  float* ws = (float*)d_ws;

  float* s0 = ws;
  float* s1 = ws + 40960;
  float* s2 = ws + 81920;
  float* oe = ws + 122880;

  hipMemsetAsync(d_ws, 0, (size_t)4 * 40960 * sizeof(float), stream);

  dim3 grid(II / ICH, BB / BTILE);  // (32, 16)
  routing_pass<0><<<grid, 256, 0, stream>>>(x, W, oe, s0, nullptr);
  squash_update<<<10, 256, 0, stream>>>(s0, oe, out, 0);
  routing_pass<1><<<grid, 256, 0, stream>>>(x, W, oe, s1, nullptr);
  squash_update<<<10, 256, 0, stream>>>(s1, oe, out, 1);
  routing_pass<2><<<grid, 256, 0, stream>>>(x, W, oe, s2, out);
  squash_update<<<10, 256, 0, stream>>>(s2, oe, out, 2);
}

// Round 2
// 233.001 us; speedup vs baseline: 2.3652x; 2.3652x over previous
//
#include <hip/hip_runtime.h>
#include <math.h>

#define II 2048
#define BB 256
#define JJ 10
#define EE 16
#define NB 2            // b's per thread
#define IW 2            // i's per staged chunk
#define ICH 16          // i's per block
#define NCH (ICH/IW)    // 8 chunks
#define ICHUNKS (II/ICH) // 128
#define BBLK 32          // b's per block (16 groups x NB)
#define SJE (BB*JJ*EE)   // 40960

typedef __attribute__((address_space(3))) unsigned lds_u32;
typedef __attribute__((address_space(1))) const unsigned glb_u32;

__device__ __forceinline__ void gload16(const float* g, float* l) {
  __builtin_amdgcn_global_load_lds((glb_u32*)g, (lds_u32*)l, 16, 0, 0);
}

// W LDS layout: per buf, per iw: 10 rows x 128 floats, linear, with XOR swizzle
// on float4-slot index: phys = logical ^ ((logical>>5)&7). DMA writes linear
// physical slots; the global SOURCE address is pre-swizzled (decode logical).
template<int PASS, bool ATOMIC>
__global__ __launch_bounds__(256)
void routing_pass(const float* __restrict__ x, const float* __restrict__ W,
                  const float* __restrict__ o_eff, float* __restrict__ sdst,
                  float* __restrict__ out) {
  __shared__ __align__(16) float w_lds[2][IW * JJ * 128]; // 2 x 2560 floats
  __shared__ __align__(16) float x_lds[2][BBLK * IW * 8]; // 2 x 512 floats

  const int t = threadIdx.x;
  const int wid = t >> 6;        // wave id 0..3
  const int g = t >> 4;          // group 0..15
  const int j = t & 15;          // capsule lane (valid < 10)
  const int b0 = blockIdx.y * BBLK;
  const int i0 = blockIdx.x * ICH;

  float o[NB][EE];
  if (PASS > 0) {
    const int jj = (j < JJ) ? j : 0;
#pragma unroll
    for (int nb = 0; nb < NB; ++nb) {
      const float* op = o_eff + ((size_t)(b0 + g * NB + nb) * JJ + jj) * EE;
#pragma unroll
      for (int q = 0; q < 4; ++q) {
        const float4 v = *reinterpret_cast<const float4*>(op + q * 4);
        o[nb][q * 4 + 0] = v.x; o[nb][q * 4 + 1] = v.y;
        o[nb][q * 4 + 2] = v.z; o[nb][q * 4 + 3] = v.w;
      }
    }
  }

  float acc[NB][EE];
#pragma unroll
  for (int nb = 0; nb < NB; ++nb)
#pragma unroll
    for (int e = 0; e < EE; ++e) acc[nb][e] = 0.f;

  auto stage = [&](int ch, int buf) {
    const int ibase = i0 + ch * IW;
    // W: 640 float4 slots (IW*10*32)
#pragma unroll
    for (int r = 0; r < 3; ++r) {
      if (r < 2 || wid < 2) {
        const int pp = r * 256 + t;                  // physical slot
        const int l = pp ^ ((pp >> 5) & 7);          // logical slot
        const int iw = (l >= 320) ? 1 : 0;
        const int rem = l - iw * 320;
        const int jr = rem >> 5, rr = rem & 31;
        const float* src = W + ((size_t)(jr * II + ibase + iw)) * 128 + rr * 4;
        gload16(src, &w_lds[buf][(r * 256 + wid * 64) * 4]);
      }
    }
    // x: 128 float4 slots, linear
    if (wid < 2) {
      const int bl = t >> 2, iw = (t >> 1) & 1, h = t & 1;
      const float* src = x + ((size_t)(b0 + bl) * II + ibase + iw) * 8 + h * 4;
      gload16(src, &x_lds[buf][wid * 256]);
    }
  };

  auto compute = [&](int ch, int buf) {
#pragma unroll
    for (int iw = 0; iw < IW; ++iw) {
      const int i = i0 + ch * IW + iw;
      float4 xa[NB], xb[NB];
#pragma unroll
      for (int nb = 0; nb < NB; ++nb) {
        const float* xp = &x_lds[buf][((g * NB + nb) * IW + iw) * 8];
        xa[nb] = *reinterpret_cast<const float4*>(xp);
        xb[nb] = *reinterpret_cast<const float4*>(xp + 4);
      }
      float uh[NB][EE];
      float lg[NB];
#pragma unroll
      for (int nb = 0; nb < NB; ++nb) lg[nb] = 0.f;
      const int key = (iw * 10 + j) & 7;
      const float* wrow = &w_lds[buf][iw * 1280 + j * 128];
      if (j < JJ) {
#pragma unroll
        for (int e = 0; e < EE; ++e) {
          const float4 w0 = *reinterpret_cast<const float4*>(&wrow[((2 * e) ^ key) * 4]);
          const float4 w1 = *reinterpret_cast<const float4*>(&wrow[((2 * e + 1) ^ key) * 4]);
#pragma unroll
          for (int nb = 0; nb < NB; ++nb) {
            float u = w0.x * xa[nb].x;
            u = fmaf(w0.y, xa[nb].y, u);
            u = fmaf(w0.z, xa[nb].z, u);
            u = fmaf(w0.w, xa[nb].w, u);
            u = fmaf(w1.x, xb[nb].x, u);
            u = fmaf(w1.y, xb[nb].y, u);
            u = fmaf(w1.z, xb[nb].z, u);
            u = fmaf(w1.w, xb[nb].w, u);
            uh[nb][e] = u;
            if (PASS > 0) lg[nb] = fmaf(o[nb][e], u, lg[nb]);
          }
        }
      }
#pragma unroll
      for (int nb = 0; nb < NB; ++nb) {
        float c;
        if (PASS == 0) {
          c = 0.1f;   // b=0 -> uniform softmax over 10
        } else {
          float lv = (j < JJ) ? lg[nb] : -INFINITY;
          float m = lv;
          m = fmaxf(m, __shfl_xor(m, 8, 16));
          m = fmaxf(m, __shfl_xor(m, 4, 16));
          m = fmaxf(m, __shfl_xor(m, 2, 16));
          m = fmaxf(m, __shfl_xor(m, 1, 16));
          float p = (j < JJ) ? __expf(lv - m) : 0.f;
          float su = p;
          su += __shfl_xor(su, 8, 16);
          su += __shfl_xor(su, 4, 16);
          su += __shfl_xor(su, 2, 16);
          su += __shfl_xor(su, 1, 16);
          c = p / su;
        }
        if (j < JJ) {
#pragma unroll
          for (int e = 0; e < EE; ++e) acc[nb][e] = fmaf(c, uh[nb][e], acc[nb][e]);
          if (PASS == 2)
            out[((size_t)(b0 + g * NB + nb) * JJ + j) * 2064 + 16 + i] = c;
        }
      }
    }
  };

  stage(0, 0);
  __syncthreads();
  for (int ch = 0; ch < NCH; ++ch) {
    const int buf = ch & 1;
    if (ch + 1 < NCH) stage(ch + 1, buf ^ 1);
    compute(ch, buf);
    __syncthreads();
  }

  if (j < JJ) {
#pragma unroll
    for (int nb = 0; nb < NB; ++nb) {
      const int b = b0 + g * NB + nb;
      if (ATOMIC) {
        float* sp = sdst + ((size_t)b * JJ + j) * EE;
#pragma unroll
        for (int e = 0; e < EE; ++e) atomicAdd(&sp[e], acc[nb][e]);
      } else {
        float* sp = sdst + (size_t)blockIdx.x * SJE + ((size_t)b * JJ + j) * EE;
        *reinterpret_cast<float4*>(sp + 0)  = make_float4(acc[nb][0],  acc[nb][1],  acc[nb][2],  acc[nb][3]);
        *reinterpret_cast<float4*>(sp + 4)  = make_float4(acc[nb][4],  acc[nb][5],  acc[nb][6],  acc[nb][7]);
        *reinterpret_cast<float4*>(sp + 8)  = make_float4(acc[nb][8],  acc[nb][9],  acc[nb][10], acc[nb][11]);
        *reinterpret_cast<float4*>(sp + 12) = make_float4(acc[nb][12], acc[nb][13], acc[nb][14], acc[nb][15]);
      }
    }
  }
}

__global__ __launch_bounds__(256)
void reduce_s(const float* __restrict__ part, float* __restrict__ s) {
  const int idx = blockIdx.x * 256 + threadIdx.x;  // < 40960
  float a = 0.f;
#pragma unroll 8
  for (int k = 0; k < ICHUNKS; ++k) a += part[(size_t)k * SJE + idx];
  s[idx] = a;
}

__global__ __launch_bounds__(256)
void squash_update(const float* __restrict__ s, float* __restrict__ o_eff,
                   float* __restrict__ out, int pass) {
  const int idx = blockIdx.x * blockDim.x + threadIdx.x;
  if (idx >= BB * JJ) return;
  const float* sp = s + (size_t)idx * EE;
  float v[EE];
  float s2 = 0.f;
#pragma unroll
  for (int e = 0; e < EE; ++e) { v[e] = sp[e]; s2 = fmaf(v[e], v[e], s2); }
  const float scale = s2 / ((1.f + s2) * sqrtf(s2 + 1e-7f));
  if (pass == 0) {
    float* op = o_eff + (size_t)idx * EE;
#pragma unroll
    for (int e = 0; e < EE; ++e) op[e] = scale * v[e];
  } else if (pass == 1) {
    float* op = o_eff + (size_t)idx * EE;
#pragma unroll
    for (int e = 0; e < EE; ++e) op[e] += scale * v[e];
  } else {
    float* dst = out + (size_t)idx * 2064;
#pragma unroll
    for (int e = 0; e < EE; ++e) dst[e] = scale * v[e];
  }
}

extern "C" void kernel_launch(void* const* d_in, const int* in_sizes, int n_in,
                              void* d_out, int out_size, void* d_ws, size_t ws_size,
                              hipStream_t stream) {
  const float* x = (const float*)d_in[0];   // [256,2048,8]
  const float* W = (const float*)d_in[1];   // [10,2048,16,8]
  float* out = (float*)d_out;               // [256,10,2064]
  float* ws = (float*)d_ws;

  const dim3 grid(ICHUNKS, BB / BBLK);      // (128, 8) = 1024 blocks
  const size_t need = ((size_t)ICHUNKS * SJE + 2 * SJE) * sizeof(float); // ~21.3 MB

  if (ws_size >= need) {
    // deterministic partial-sum path (no atomics)
    float* part = ws;
    float* s    = ws + (size_t)ICHUNKS * SJE;
    float* oe   = s + SJE;
    routing_pass<0, false><<<grid, 256, 0, stream>>>(x, W, nullptr, part, nullptr);
    reduce_s<<<SJE / 256, 256, 0, stream>>>(part, s);
    squash_update<<<10, 256, 0, stream>>>(s, oe, out, 0);
    routing_pass<1, false><<<grid, 256, 0, stream>>>(x, W, oe, part, nullptr);
    reduce_s<<<SJE / 256, 256, 0, stream>>>(part, s);
    squash_update<<<10, 256, 0, stream>>>(s, oe, out, 1);
    routing_pass<2, false><<<grid, 256, 0, stream>>>(x, W, oe, part, out);
    reduce_s<<<SJE / 256, 256, 0, stream>>>(part, s);
    squash_update<<<10, 256, 0, stream>>>(s, oe, out, 2);
  } else {
    // atomic fallback (round-1-proven)
    float* s0 = ws;
    float* s1 = ws + SJE;
    float* s2 = ws + 2 * SJE;
    float* oe = ws + 3 * SJE;
    hipMemsetAsync(ws, 0, (size_t)4 * SJE * sizeof(float), stream);
    routing_pass<0, true><<<grid, 256, 0, stream>>>(x, W, nullptr, s0, nullptr);
    squash_update<<<10, 256, 0, stream>>>(s0, oe, out, 0);
    routing_pass<1, true><<<grid, 256, 0, stream>>>(x, W, oe, s1, nullptr);
    squash_update<<<10, 256, 0, stream>>>(s1, oe, out, 1);
    routing_pass<2, true><<<grid, 256, 0, stream>>>(x, W, oe, s2, out);
    squash_update<<<10, 256, 0, stream>>>(s2, oe, out, 2);
  }
}